// Round 6
// baseline (128.880 us; speedup 1.0000x reference)
//
#include <hip/hip_runtime.h>

// Kalman filter, reformulated:  out[b][p] = alpha_p + sum_t Z[p][t] x[b][t]
// 15 blocks x 512:
//   block 0   : 64x64 Riccati recursion -> gains k_t. Transpose-free MFMA chain:
//               mm1: U = P_work^T F^T (A = PF tile-swapped D-frags, B = Fh),
//               mm2: Ppred = U^T F^T  (A = TF tile-swapped D-frags, B = Fh).
//               All LDS lane-linear vector ops; k/hP via broadcast float4 reads.
//   block 1   : prediction-phase row chains u_p, e_p
//   blocks 2-6: 33 V-column chains (1 wave each), consume tagged k_t (s_sleep)
//   blocks 7-14: output GEMM; gated by done-counter, then tagged reads
// ws (u64): KP[32*64] (tag t+1) | WP[33*64] | UP[16*64] | EP[16] | CNT (tag 1)

constexpr int KP_OFF = 0;
constexpr int WP_OFF = 2048;
constexpr int UP_OFF = 4160;
constexpr int EP_OFF = 5184;
constexpr int CNT_OFF = 5200;
constexpr int WS_U64 = 5201;

typedef float    f32x4 __attribute__((ext_vector_type(4)));
typedef _Float16 f16x4 __attribute__((ext_vector_type(4)));

#define MFMA16(a, b, c) __builtin_amdgcn_mfma_f32_16x16x16f16((a), (b), (c), 0, 0, 0)

template <int CTRL>
__device__ __forceinline__ float dpp_add(float x) {
  int v = __builtin_amdgcn_update_dpp(0, __builtin_bit_cast(int, x), CTRL, 0xf, 0xf, true);
  return x + __builtin_bit_cast(float, v);
}
__device__ __forceinline__ float sum16(float x) {  // full sum within 16-lane rows
  x = dpp_add<0xB1>(x);   // quad_perm xor1
  x = dpp_add<0x4E>(x);   // quad_perm xor2
  x = dpp_add<0x141>(x);  // row_half_mirror (xor4)
  x = dpp_add<0x140>(x);  // row_mirror (xor8)
  return x;
}

__device__ __forceinline__ float spin_read(const unsigned long long* p, unsigned tag) {
  unsigned long long v = 0;
  for (int it = 0; it < (1 << 22); ++it) {
    v = __hip_atomic_load(p, __ATOMIC_RELAXED, __HIP_MEMORY_SCOPE_AGENT);
    if ((unsigned)(v >> 32) == tag) break;
  }
  union { unsigned u; float f; } cv; cv.u = (unsigned)v;
  return cv.f;
}
__device__ __forceinline__ float spin_read_sleep(const unsigned long long* p, unsigned tag) {
  unsigned long long v = 0;
  for (int it = 0; it < (1 << 20); ++it) {
    v = __hip_atomic_load(p, __ATOMIC_RELAXED, __HIP_MEMORY_SCOPE_AGENT);
    if ((unsigned)(v >> 32) == tag) break;
    __builtin_amdgcn_s_sleep(2);
  }
  union { unsigned u; float f; } cv; cv.u = (unsigned)v;
  return cv.f;
}
__device__ __forceinline__ void pub_write(unsigned long long* p, unsigned tag, float x) {
  union { float f; unsigned u; } cv; cv.f = x;
  __hip_atomic_store(p, ((unsigned long long)tag << 32) | cv.u,
                     __ATOMIC_RELAXED, __HIP_MEMORY_SCOPE_AGENT);
}
// Barrier waiting only LDS ops — global prefetch stays in flight.
__device__ __forceinline__ void lds_barrier() {
  asm volatile("s_waitcnt lgkmcnt(0)" ::: "memory");
  __builtin_amdgcn_sched_barrier(0);
  __builtin_amdgcn_s_barrier();
  __builtin_amdgcn_sched_barrier(0);
}

__global__ __launch_bounds__(512) void kalman_fused(
    const float* __restrict__ Fw, const float* __restrict__ Fb,
    const float* __restrict__ Hw, const float* __restrict__ Hb,
    const float* __restrict__ s0, const float* __restrict__ P0,
    const float* __restrict__ Qg, const float* __restrict__ Rg,
    const float* __restrict__ x, float* __restrict__ out,
    unsigned long long* __restrict__ ws) {
  __shared__ __align__(16) char smem[43008];
  const int tid  = threadIdx.x;
  const int lane = tid & 63;
  const int w    = tid >> 6;
  const int blk  = blockIdx.x;
  unsigned long long* kp = ws + KP_OFF;
  unsigned long long* wp = ws + WP_OFF;
  unsigned long long* up = ws + UP_OFF;
  unsigned long long* ep = ws + EP_OFF;

  if (blk == 0) {
    // ================= P/k Riccati recursion =================
    _Float16* FFh = (_Float16*)smem;            // [16][64][4]  F hi frags
    _Float16* TF  = (_Float16*)(smem + 8192);   // [16][64][4]  U frags (f16)
    float*    PF  = (float*)(smem + 16384);     // [16][64][4]  Ppred D-frags f32
    float*    Hws = (float*)(smem + 32768);     // [32][64]
    float*    nred = (float*)(smem + 40960);    // [2][64]  num partials
    float*    mred = (float*)(smem + 41472);    // [4][64]  hP partials
    float*    Sred = (float*)(smem + 42496);    // [8]

    const int l15 = lane & 15, g = lane >> 4;
    const int ti = w >> 1, half = w & 1;
    const int tj0 = 2 * half, tj1 = 2 * half + 1;
    const int sr = tid >> 3, sc0 = (tid & 7) * 8;
    const int fi0 = (sr >> 4) * 4 + (sc0 >> 4);
    const int L0  = (sr & 15) + 16 * ((sc0 & 15) >> 2);
    const float R0 = Rg[0];

    auto stageFh = [&](f32x4 a, f32x4 b) {
      f16x4 pa, pb;
      #pragma unroll
      for (int u = 0; u < 4; ++u) { pa[u] = (_Float16)a[u]; pb[u] = (_Float16)b[u]; }
      *(f16x4*)&FFh[(fi0 * 64 + L0) * 4]      = pa;
      *(f16x4*)&FFh[(fi0 * 64 + L0 + 16) * 4] = pb;
    };

    // ---- prologue ----
    f32x4 qf0, qf1;
    #pragma unroll
    for (int reg = 0; reg < 4; ++reg) {
      qf0[reg] = Qg[(16 * ti + 4 * g + reg) * 64 + 16 * tj0 + l15];
      qf1[reg] = Qg[(16 * ti + 4 * g + reg) * 64 + 16 * tj1 + l15];
    }
    for (int idx = tid; idx < 2048; idx += 512) Hws[idx] = Hw[idx];
    #pragma unroll
    for (int s = 0; s < 2; ++s) {  // P0 -> PF as D-frags
      const int slot = tid + s * 512;
      const int f = slot >> 6, ln = slot & 63;
      const int a = f >> 2, b = f & 3, g2 = ln >> 4, l2 = ln & 15;
      f32x4 v;
      #pragma unroll
      for (int r = 0; r < 4; ++r)
        v[r] = P0[(16 * a + 4 * g2 + r) * 64 + 16 * b + l2];
      *(f32x4*)&PF[(f * 64 + ln) * 4] = v;
    }
    {  // stage F_0
      f32x4 a = *(const f32x4*)(Fw + sr * 64 + sc0);
      f32x4 b = *(const f32x4*)(Fw + sr * 64 + sc0 + 4);
      stageFh(a, b);
    }
    for (int idx = tid; idx < 2 * 64; idx += 512) nred[idx] = 0.f;
    for (int idx = tid; idx < 4 * 64; idx += 512) mred[idx] = 0.f;
    if (tid < 8) Sred[tid] = 0.f;
    __syncthreads();

    f32x4 fna, fnb;
    for (int t = 0; t < 32; ++t) {
      // ---- phase 1: k-finalize + A-cvt + B-read + mm1 ----
      if (t + 1 < 32) {
        fna = *(const f32x4*)(Fw + (size_t)(t + 1) * 4096 + sr * 64 + sc0);
        fnb = *(const f32x4*)(Fw + (size_t)(t + 1) * 4096 + sr * 64 + sc0 + 4);
      }
      float S;
      {
        const f32x4 sa = *(const f32x4*)&Sred[0];
        const f32x4 sb = *(const f32x4*)&Sred[4];
        S = ((sa.x + sa.y) + (sa.z + sa.w)) + ((sb.x + sb.y) + (sb.z + sb.w));
      }
      const float rcpS = 1.0f / (S + R0);
      const int ia = 16 * ti + l15;
      const float hPl = mred[ia] + mred[64 + ia] + mred[128 + ia] + mred[192 + ia];

      f16x4 Ah[4], Al[4];
      #pragma unroll
      for (int kc = 0; kc < 4; ++kc) {
        const int na = 16 * kc + 4 * g;
        const f32x4 n4 = *(const f32x4*)&nred[na] + *(const f32x4*)&nred[64 + na];
        const f32x4 k4 = n4 * rcpS;
        const f32x4 p4 = *(const f32x4*)&PF[((kc * 4 + ti) * 64 + lane) * 4] - k4 * hPl;
        #pragma unroll
        for (int j = 0; j < 4; ++j) {
          const _Float16 h_ = (_Float16)p4[j];
          Ah[kc][j] = h_;
          Al[kc][j] = (_Float16)((p4[j] - (float)h_) * 2048.0f);
        }
      }
      f16x4 Bf[2][4];
      #pragma unroll
      for (int s2 = 0; s2 < 2; ++s2) {
        const int tj = tj0 + s2;
        #pragma unroll
        for (int kc = 0; kc < 4; ++kc)
          Bf[s2][kc] = *(const f16x4*)&FFh[((tj * 4 + kc) * 64 + lane) * 4];
      }
      if (w == 0 && t > 0) {  // publish k_{t-1}
        const float kl = (nred[lane] + nred[64 + lane]) * rcpS;
        pub_write(&kp[(t - 1) * 64 + lane], (unsigned)t, kl);
      }
      #pragma unroll
      for (int s2 = 0; s2 < 2; ++s2) {  // mm1: U = P_work^T F^T
        const int tj = tj0 + s2;
        f32x4 am = {0.f, 0.f, 0.f, 0.f}, a2 = {0.f, 0.f, 0.f, 0.f};
        #pragma unroll
        for (int kc = 0; kc < 4; ++kc) {
          am = MFMA16(Ah[kc], Bf[s2][kc], am);
          a2 = MFMA16(Al[kc], Bf[s2][kc], a2);
        }
        const f32x4 uv = am + a2 * (1.0f / 2048.0f);
        f16x4 uh;
        #pragma unroll
        for (int j = 0; j < 4; ++j) uh[j] = (_Float16)uv[j];
        *(f16x4*)&TF[((ti * 4 + tj) * 64 + lane) * 4] = uh;
      }
      lds_barrier();  // A

      // ---- phase 2: stage F_{t+1} + mm2 + reductions ----
      if (t + 1 < 32) stageFh(fna, fnb);
      f16x4 Ua[4];
      #pragma unroll
      for (int kc = 0; kc < 4; ++kc)
        Ua[kc] = *(const f16x4*)&TF[((kc * 4 + ti) * 64 + lane) * 4];
      f32x4 pout[2];
      #pragma unroll
      for (int s2 = 0; s2 < 2; ++s2) {  // mm2: Ppred = U^T F^T (+Q)
        const int tj = tj0 + s2;
        f32x4 acc = {0.f, 0.f, 0.f, 0.f};
        #pragma unroll
        for (int kc = 0; kc < 4; ++kc) acc = MFMA16(Ua[kc], Bf[s2][kc], acc);
        acc += (s2 ? qf1 : qf0);
        pout[s2] = acc;
        *(f32x4*)&PF[((ti * 4 + tj) * 64 + lane) * 4] = acc;
      }
      const float hcA = Hws[t * 64 + 16 * tj0 + l15];
      const float hcB = Hws[t * 64 + 16 * tj1 + l15];
      const f32x4 h4 = *(const f32x4*)&Hws[t * 64 + 16 * ti + 4 * g];
      const f32x4 npv = pout[0] * hcA + pout[1] * hcB;
      const float np0 = sum16(npv.x), np1 = sum16(npv.y);
      const float np2 = sum16(npv.z), np3 = sum16(npv.w);
      float sel = np0;
      sel = (l15 == 1) ? np1 : sel;
      sel = (l15 == 2) ? np2 : sel;
      sel = (l15 == 3) ? np3 : sel;
      if (l15 < 4) nred[half * 64 + 16 * ti + 4 * g + l15] = sel;
      float mp0 = pout[0].x * h4.x + pout[0].y * h4.y + pout[0].z * h4.z + pout[0].w * h4.w;
      float mp1 = pout[1].x * h4.x + pout[1].y * h4.y + pout[1].z * h4.z + pout[1].w * h4.w;
      mp0 += __shfl_xor(mp0, 16, 64); mp0 += __shfl_xor(mp0, 32, 64);
      mp1 += __shfl_xor(mp1, 16, 64); mp1 += __shfl_xor(mp1, 32, 64);
      if (g == 0) {
        mred[ti * 64 + 16 * tj0 + l15] = mp0;
        mred[ti * 64 + 16 * tj1 + l15] = mp1;
      }
      float sp = npv.x * h4.x + npv.y * h4.y + npv.z * h4.z + npv.w * h4.w;
      sp = sum16(sp);
      sp += __shfl_xor(sp, 16, 64); sp += __shfl_xor(sp, 32, 64);
      if (lane == 0) Sred[w] = sp;
      lds_barrier();  // B
    }
    if (w == 0) {  // finalize + publish k_31
      const f32x4 sa = *(const f32x4*)&Sred[0];
      const f32x4 sb = *(const f32x4*)&Sred[4];
      const float S = ((sa.x + sa.y) + (sa.z + sa.w)) + ((sb.x + sb.y) + (sb.z + sb.w));
      const float kl = (nred[lane] + nred[64 + lane]) / (S + R0);
      pub_write(&kp[31 * 64 + lane], 32u, kl);
    }
    return;
  }

  if (blk == 1) {
    // ================= prediction-phase chains u_p, e_p =================
    for (int pi = 0; pi < 2; ++pi) {
      const int p = pi ? (15 - w) : w;
      const int q = 32 + p;
      float r = Hw[q * 64 + lane];
      float eacc = 0.f;
      for (int s = 0; s <= p; ++s) {
        const int m = q - s;
        eacc += r * Fb[m * 64 + lane];
        const float* Fm = Fw + (size_t)m * 4096;
        float r0 = 0.f, r1 = 0.f, r2 = 0.f, r3 = 0.f;
        for (int j = 0; j < 64; j += 4) {
          r0 += __shfl(r, j,     64) * Fm[j * 64 + lane];
          r1 += __shfl(r, j + 1, 64) * Fm[(j + 1) * 64 + lane];
          r2 += __shfl(r, j + 2, 64) * Fm[(j + 2) * 64 + lane];
          r3 += __shfl(r, j + 3, 64) * Fm[(j + 3) * 64 + lane];
        }
        r = (r0 + r1) + (r2 + r3);
      }
      eacc = sum16(eacc);
      eacc += __shfl_xor(eacc, 16, 64); eacc += __shfl_xor(eacc, 32, 64);
      pub_write(&up[p * 64 + lane], 1u, r);
      if (lane == 0) pub_write(&ep[p], 1u, eacc + Hb[q]);
    }
    __syncthreads();
    if (tid == 0)
      __hip_atomic_fetch_add(&ws[CNT_OFF], 1ull, __ATOMIC_RELAXED, __HIP_MEMORY_SCOPE_AGENT);
    return;
  }

  if (blk < 7) {
    // ================= V-column chains (1 wave per column) =================
    float* vb = (float*)smem + w * 64;
    const int c = (blk - 2) * 8 + w;
    if (c > 32) return;
    if (c == 32) {  // w_31 = k_31
      pub_write(&wp[32 * 64 + lane], 1u, spin_read_sleep(&kp[31 * 64 + lane], 32u));
      if (lane == 0)
        __hip_atomic_fetch_add(&ws[CNT_OFF], 1ull, __ATOMIC_RELAXED, __HIP_MEMORY_SCOPE_AGENT);
      return;
    }
    const int t0 = (c == 0) ? 0 : c;
    float v = (c == 0) ? s0[lane] : spin_read_sleep(&kp[(c - 1) * 64 + lane], (unsigned)c);
    f32x4 fn[16];
    {
      const float* Fr = Fw + (size_t)t0 * 4096 + lane * 64;
      #pragma unroll
      for (int jc = 0; jc < 16; ++jc) fn[jc] = *(const f32x4*)(Fr + jc * 4);
    }
    float hn  = Hw[t0 * 64 + lane];
    float fbn = (c == 0) ? Fb[t0 * 64 + lane] : 0.f;
    for (int t = t0; t < 32; ++t) {
      vb[lane] = v;
      f32x4 fc[16];
      #pragma unroll
      for (int jc = 0; jc < 16; ++jc) fc[jc] = fn[jc];
      const float ht = hn, fbt = fbn;
      if (t + 1 < 32) {
        const float* Fr = Fw + (size_t)(t + 1) * 4096 + lane * 64;
        #pragma unroll
        for (int jc = 0; jc < 16; ++jc) fn[jc] = *(const f32x4*)(Fr + jc * 4);
        hn = Hw[(t + 1) * 64 + lane];
        if (c == 0) fbn = Fb[(t + 1) * 64 + lane];
      }
      float a0 = fbt, a1 = 0.f, a2 = 0.f, a3 = 0.f;
      #pragma unroll
      for (int jc = 0; jc < 16; ++jc) {
        const f32x4 vv = *(const f32x4*)(vb + jc * 4);
        a0 += fc[jc].x * vv.x; a1 += fc[jc].y * vv.y;
        a2 += fc[jc].z * vv.z; a3 += fc[jc].w * vv.w;
      }
      const float vp = (a0 + a1) + (a2 + a3);
      float hv = ht * vp;
      hv = sum16(hv);
      hv += __shfl_xor(hv, 16, 64); hv += __shfl_xor(hv, 32, 64);
      if (c == 0) hv += Hb[t];
      const float kt = spin_read_sleep(&kp[t * 64 + lane], (unsigned)(t + 1));
      v = vp - kt * hv;
    }
    pub_write(&wp[c * 64 + lane], 1u, v);
    if (lane == 0)
      __hip_atomic_fetch_add(&ws[CNT_OFF], 1ull, __ATOMIC_RELAXED, __HIP_MEMORY_SCOPE_AGENT);
    return;
  }

  // ================= output GEMM blocks (blk 7..14) =================
  {
    float* Ul = (float*)smem;             // [16][68]
    float* Wl = (float*)(smem + 4352);    // [33][68]
    float* Zl = (float*)(smem + 13328);   // [16][34]
    float* El = (float*)(smem + 15504);   // [16]
    const int b = (blk - 7) * 512 + tid;
    f32x4 xr[8];
    const f32x4* xp = (const f32x4*)(x + (size_t)b * 32);
    #pragma unroll
    for (int u = 0; u < 8; ++u) xr[u] = xp[u];

    if (tid == 0) {
      for (int it = 0; it < (1 << 20); ++it) {
        if (__hip_atomic_load(&ws[CNT_OFF], __ATOMIC_RELAXED, __HIP_MEMORY_SCOPE_AGENT) >= 34ull)
          break;
        __builtin_amdgcn_s_sleep(8);
      }
    }
    __syncthreads();
    for (int idx = tid; idx < 1024; idx += 512)
      Ul[(idx >> 6) * 68 + (idx & 63)] = spin_read(&up[idx], 1u);
    for (int idx = tid; idx < 2112; idx += 512)
      Wl[(idx >> 6) * 68 + (idx & 63)] = spin_read(&wp[idx], 1u);
    if (tid < 16) El[tid] = spin_read(&ep[tid], 1u);
    __syncthreads();
    for (int idx = tid; idx < 528; idx += 512) {
      const int p = idx / 33, cc = idx - p * 33;
      const float* Up = Ul + p * 68;
      const float* Wc = Wl + cc * 68;
      float a0 = 0.f, a1 = 0.f, a2 = 0.f, a3 = 0.f;
      #pragma unroll 4
      for (int i = 0; i < 64; i += 4) {
        a0 += Up[i] * Wc[i];         a1 += Up[i + 1] * Wc[i + 1];
        a2 += Up[i + 2] * Wc[i + 2]; a3 += Up[i + 3] * Wc[i + 3];
      }
      float z = (a0 + a1) + (a2 + a3);
      if (cc == 0) z += El[p];
      Zl[p * 34 + cc] = z;
    }
    __syncthreads();
    float acc[16];
    #pragma unroll
    for (int p = 0; p < 16; ++p) acc[p] = Zl[p * 34];
    #pragma unroll
    for (int u = 0; u < 8; ++u) {
      #pragma unroll
      for (int e = 0; e < 4; ++e) {
        const float xval = xr[u][e];
        const int t = u * 4 + e;
        #pragma unroll
        for (int p = 0; p < 16; ++p) acc[p] += Zl[p * 34 + 1 + t] * xval;
      }
    }
    float4* op = (float4*)(out + (size_t)b * 16);
    op[0] = make_float4(acc[0], acc[1], acc[2], acc[3]);
    op[1] = make_float4(acc[4], acc[5], acc[6], acc[7]);
    op[2] = make_float4(acc[8], acc[9], acc[10], acc[11]);
    op[3] = make_float4(acc[12], acc[13], acc[14], acc[15]);
  }
}

extern "C" void kernel_launch(void* const* d_in, const int* in_sizes, int n_in,
                              void* d_out, int out_size, void* d_ws, size_t ws_size,
                              hipStream_t stream) {
  (void)in_sizes; (void)n_in; (void)out_size; (void)ws_size;
  const float* x  = (const float*)d_in[0];
  const float* Fw = (const float*)d_in[1];
  const float* Fb = (const float*)d_in[2];
  const float* Hw = (const float*)d_in[3];
  const float* Hb = (const float*)d_in[4];
  const float* s0 = (const float*)d_in[5];
  const float* P0 = (const float*)d_in[6];
  const float* Q  = (const float*)d_in[7];
  const float* R  = (const float*)d_in[8];
  float* out = (float*)d_out;
  unsigned long long* ws = (unsigned long long*)d_ws;

  hipMemsetAsync(d_ws, 0, WS_U64 * sizeof(unsigned long long), stream);
  kalman_fused<<<15, 512, 0, stream>>>(Fw, Fb, Hw, Hb, s0, P0, Q, R, x, out, ws);
}